// Round 6
// baseline (220.320 us; speedup 1.0000x reference)
//
#include <hip/hip_runtime.h>

#define IN_DIM  2048   // K
#define OUT_DIM 2048   // N
#define MROWS   8192   // M = B*S
#define RANK    4
#define BK      64

typedef unsigned short ushort_t;
typedef __attribute__((ext_vector_type(8))) short  short8;   // 8 bf16 (4 VGPRs)
typedef __attribute__((ext_vector_type(4))) float  floatx4;  // MFMA acc

__device__ __forceinline__ unsigned short f2bf(float f) {
  union { float f; unsigned int u; } v; v.f = f;
  unsigned int r = v.u + 0x7fffu + ((v.u >> 16) & 1u);  // RNE
  return (unsigned short)(r >> 16);
}

__device__ __forceinline__ void gload16(const ushort_t* g, short* l) {
  __builtin_amdgcn_global_load_lds(
      (const __attribute__((address_space(1))) void*)g,
      (__attribute__((address_space(3))) void*)l, 16, 0, 0);
}

// ---- kernel 1: rank coefficients c[r] = softplus(mag)/(||A[:,r]|| * ||B[r,:]||) ----
__global__ void coef_kernel(const float* __restrict__ sA, const float* __restrict__ sB,
                            const float* __restrict__ mag, float* __restrict__ cOut) {
  __shared__ float part[8][256];
  __shared__ float tot[8];
  int t = threadIdx.x;
  float sa[4] = {0.f, 0.f, 0.f, 0.f};
  for (int o = t; o < OUT_DIM; o += 256) {
    float4 v = *(const float4*)(sA + o * 4);
    sa[0] += v.x * v.x; sa[1] += v.y * v.y; sa[2] += v.z * v.z; sa[3] += v.w * v.w;
  }
  float sb[4] = {0.f, 0.f, 0.f, 0.f};
  for (int r = 0; r < 4; ++r)
    for (int i = t; i < IN_DIM; i += 256) { float v = sB[r * IN_DIM + i]; sb[r] += v * v; }
  for (int q = 0; q < 4; ++q) { part[q][t] = sa[q]; part[4 + q][t] = sb[q]; }
  __syncthreads();
  if (t < 8) { float s = 0.f; for (int j = 0; j < 256; ++j) s += part[t][j]; tot[t] = s; }
  __syncthreads();
  if (t < 4) {
    float g  = log1pf(expf(mag[t])) + 1e-6f;        // softplus + mag_eps
    float na = fmaxf(sqrtf(tot[t]),     1e-6f);
    float nb = fmaxf(sqrtf(tot[4 + t]), 1e-6f);
    cOut[t] = g / (na * nb);
  }
}

// ---- kernel 2 (fused): blocks [0,8192): cast x->bf16; blocks [8192,10240): build W ----
__global__ void prep_kernel(const float* __restrict__ x, ushort_t* __restrict__ xb,
                            const int* __restrict__ idx, const float* __restrict__ lut,
                            const float* __restrict__ sA, const float* __restrict__ sB,
                            const float* __restrict__ c, ushort_t* __restrict__ W) {
  int t = threadIdx.x;
  if (blockIdx.x < 8192) {
    size_t i = ((size_t)blockIdx.x * 256 + t) * 8;
    float4 a = *(const float4*)(x + i);
    float4 b = *(const float4*)(x + i + 4);
    uint4 o4;
    o4.x = (unsigned)f2bf(a.x) | ((unsigned)f2bf(a.y) << 16);
    o4.y = (unsigned)f2bf(a.z) | ((unsigned)f2bf(a.w) << 16);
    o4.z = (unsigned)f2bf(b.x) | ((unsigned)f2bf(b.y) << 16);
    o4.w = (unsigned)f2bf(b.z) | ((unsigned)f2bf(b.w) << 16);
    *(uint4*)(xb + i) = o4;
  } else {
    __shared__ float aA[4];
    __shared__ float lutS[16];
    int o = blockIdx.x - 8192;
    if (t < 4)  aA[t]   = fabsf(sA[o * 4 + t]) * c[t];
    if (t < 16) lutS[t] = lut[t];
    __syncthreads();
    int i = t * 8;
    const int4* ip4 = (const int4*)(idx + (size_t)o * IN_DIM + i);
    int4 i0 = ip4[0], i1 = ip4[1];
    int ii[8] = {i0.x, i0.y, i0.z, i0.w, i1.x, i1.y, i1.z, i1.w};
    unsigned short u[8];
    #pragma unroll
    for (int j = 0; j < 8; ++j) {
      float s = aA[0] * fabsf(sB[0 * IN_DIM + i + j])
              + aA[1] * fabsf(sB[1 * IN_DIM + i + j])
              + aA[2] * fabsf(sB[2 * IN_DIM + i + j])
              + aA[3] * fabsf(sB[3 * IN_DIM + i + j]);
      u[j] = f2bf(lutS[ii[j]] * s);
    }
    uint4 o4;
    o4.x = (unsigned)u[0] | ((unsigned)u[1] << 16);
    o4.y = (unsigned)u[2] | ((unsigned)u[3] << 16);
    o4.z = (unsigned)u[4] | ((unsigned)u[5] << 16);
    o4.w = (unsigned)u[6] | ((unsigned)u[7] << 16);
    *(uint4*)(W + (size_t)o * IN_DIM + i) = o4;
  }
}

// ============================================================================
// kernel 3: C[M,N] = A[M,K] * W[N,K]^T + bias
// 256x256 tile, BK=64, 8 waves (2x4), 8-phase counted-vmcnt schedule.
// R2: XCD-chunked tile remap (FETCH 135->49 MB, verified).
// R3-R5: fence removal, read-after-barrier variants, 1-phase A-pipeline: all
//   NULL (~1480 cyc/phase). Corrected LDS model (256 B/cyc/CU aggregate):
//   phase floor = 620 cyc MFMA + ~200 LDS wait; m201's 824 matches; our 1480
//   has ~550 cyc unexplained by any read-after-barrier model.
// R6 (this round): LITERAL m201 phase skeleton -- the one untested structural
//   delta: ds_reads for the CURRENT phase issued BEFORE the barrier, consumed
//   via lgkmcnt(0) right after it (reads serviced while waves drain into the
//   barrier; m196: this fine interleave is the lever, -7..-27% without it).
//   sched_barrier(0) fences pin issue-before-barrier and MFMA-after-wait
//   (s_barrier is NOT an IR memory fence; compiler may otherwise sink the
//   loads). MFMA cluster reordered all-k0-then-all-k1 (no dependent
//   back-to-back acc pairs). No reg ping-pong.
// Stage plan per iter i (tiles u=2i buf0, u+1 buf1):
//   P1 lA1.Ah1(u+1)   P2 lB0.Bh0(u+2)  P3 lB0.Bh1(u+2)  P4 lA0.Ah0(u+2) vm6
//   P5 lA0.Ah1(u+2)   P6 lB1.Bh0(u+3)  P7 lB1.Bh1(u+3)  P8 lA1.Ah0(u+3) vm6
// vmcnt(6)@P4 retires prev P6..P8+P1 -> buf1 landed (read from P5).
// vmcnt(6)@P8 retires P2..P5 -> buf0' landed (read from next P1).
// RAW: each phase's reads are issued after the barrier-pair of the phase whose
// vmcnt proved the buffer landed. WAR: each stage is issued >=1 barrier after
// the lgkmcnt(0) retire point of the region's last reader. Last iter: P4 vm0.
// ============================================================================

#define MFMA16(a, b, c) __builtin_amdgcn_mfma_f32_16x16x32_bf16(a, b, c, 0, 0, 0)

// stage one A/B half-tile (h) of K-tile `tile` into `ldsbase` (2 x gload16/thread)
__device__ __forceinline__ void stage_half(const ushort_t* gbase, short* ldsbase,
                                           int tile, int h, int wid) {
  gload16(gbase + (size_t)h * 64 * IN_DIM + (size_t)tile * BK,
          ldsbase + (h * 512 + wid * 64) * 8);
  gload16(gbase + ((size_t)h * 64 + 128) * IN_DIM + (size_t)tile * BK,
          ldsbase + (1024 + h * 512 + wid * 64) * 8);
}

// m201 skeleton: reads -> stage -> [hints] -> barrier -> lgkmcnt(0) -> MFMA -> barrier
template <int MQ, bool FIRST, typename StageFn>
__device__ __forceinline__ void phase(const short* aRd, const short* bRd,
                                      int ko0, int ko1,
                                      floatx4 (&acc)[8][4], short8 (&bf)[8],
                                      StageFn&& stage, int vm) {
  short8 a0k0 = *(const short8*)(aRd + (2 * MQ) * 1024 + ko0);
  short8 a0k1 = *(const short8*)(aRd + (2 * MQ) * 1024 + ko1);
  short8 a1k0 = *(const short8*)(aRd + (2 * MQ + 1) * 1024 + ko0);
  short8 a1k1 = *(const short8*)(aRd + (2 * MQ + 1) * 1024 + ko1);
  if (FIRST) {
    #pragma unroll
    for (int ni = 0; ni < 4; ++ni) {
      bf[ni]     = *(const short8*)(bRd + ni * 1024 + ko0);
      bf[4 + ni] = *(const short8*)(bRd + ni * 1024 + ko1);
    }
  }
  stage();
  if (FIRST)        asm volatile("s_waitcnt lgkmcnt(8)");  // bound pre-barrier DS queue
  if (vm == 6)      asm volatile("s_waitcnt vmcnt(6)");
  else if (vm == 0) asm volatile("s_waitcnt vmcnt(0)");
  __builtin_amdgcn_sched_barrier(0);     // pin reads/stage ABOVE the barrier
  __builtin_amdgcn_s_barrier();
  asm volatile("s_waitcnt lgkmcnt(0)");
  __builtin_amdgcn_sched_barrier(0);     // rule #18: keep MFMA below the wait
  __builtin_amdgcn_s_setprio(1);
  #pragma unroll
  for (int ni = 0; ni < 4; ++ni)
    acc[2 * MQ    ][ni] = MFMA16(a0k0, bf[ni],     acc[2 * MQ    ][ni]);
  #pragma unroll
  for (int ni = 0; ni < 4; ++ni)
    acc[2 * MQ + 1][ni] = MFMA16(a1k0, bf[ni],     acc[2 * MQ + 1][ni]);
  #pragma unroll
  for (int ni = 0; ni < 4; ++ni)
    acc[2 * MQ    ][ni] = MFMA16(a0k1, bf[4 + ni], acc[2 * MQ    ][ni]);
  #pragma unroll
  for (int ni = 0; ni < 4; ++ni)
    acc[2 * MQ + 1][ni] = MFMA16(a1k1, bf[4 + ni], acc[2 * MQ + 1][ni]);
  __builtin_amdgcn_s_setprio(0);
  __builtin_amdgcn_s_barrier();
}

__global__ __launch_bounds__(512, 2) void gemm_kernel(const ushort_t* __restrict__ A,
                                                      const ushort_t* __restrict__ W,
                                                      const float* __restrict__ bias,
                                                      float* __restrict__ C) {
  __shared__ short lA0[16384];   // 256x64 bf16 = 32 KiB each, 128 KiB total
  __shared__ short lB0[16384];
  __shared__ short lA1[16384];
  __shared__ short lB1[16384];

  const int t    = threadIdx.x;
  const int lane = t & 63;
  const int wid  = t >> 6;       // 8 waves: 2 (M) x 4 (N)
  const int wr   = wid >> 2;
  const int wc   = wid & 3;

  // XCD-chunked tile remap (R2). flat id in hw dispatch order:
  const int flat  = blockIdx.y * 8 + blockIdx.x;   // x-fastest
  const int xcd   = flat & 7;                      // round-robin XCD assignment
  const int slot  = flat >> 3;                     // 0..31: CU slot within XCD
  const int tileY = (xcd >> 1) * 8 + (slot >> 2);  // 8 consecutive y-tiles / XCD
  const int tileX = (xcd & 1) * 4 + (slot & 3);    // 4 consecutive x-tiles / XCD
  const int rowBase = tileY * 256;
  const int colBase = tileX * 256;

  // staging source: thread covers row srcRow of each 64-row quadrant, chunk pre-swizzled
  const int srcRow   = wid * 8 + (lane >> 3);
  const int srcChunk = (lane & 7) ^ (lane >> 3);   // slot ^ (row&7)
  const ushort_t* gA = A + (size_t)(rowBase + srcRow) * IN_DIM + srcChunk * 8;
  const ushort_t* gB = W + (size_t)(colBase + srcRow) * IN_DIM + srcChunk * 8;

  // fragment-read addressing
  const int rA  = lane & 15;
  const int kh  = lane >> 4;
  const int sw  = rA & 7;
  const int ko0 = ((kh)     ^ sw) * 8;   // kk=0 chunk, swizzled, in shorts
  const int ko1 = ((4 + kh) ^ sw) * 8;   // kk=1
  const short* aRd0 = lA0 + (wr * 128 + rA) * 64;
  const short* bRd0 = lB0 + (wc * 64  + rA) * 64;
  const short* aRd1 = lA1 + (wr * 128 + rA) * 64;
  const short* bRd1 = lB1 + (wc * 64  + rA) * 64;

  floatx4 acc[8][4];
  #pragma unroll
  for (int i = 0; i < 8; ++i)
    #pragma unroll
    for (int j = 0; j < 4; ++j) acc[i][j] = (floatx4){0.f, 0.f, 0.f, 0.f};
  short8 bf[8];

  // prologue: tile0 complete (8 loads), then tile1 Bh0,Bh1,Ah0 (6 loads)
  stage_half(gA, lA0, 0, 0, wid);
  stage_half(gA, lA0, 0, 1, wid);
  stage_half(gB, lB0, 0, 0, wid);
  stage_half(gB, lB0, 0, 1, wid);
  stage_half(gB, lB1, 1, 0, wid);
  stage_half(gB, lB1, 1, 1, wid);
  stage_half(gA, lA1, 1, 0, wid);
  asm volatile("s_waitcnt vmcnt(6)");   // tile0's 8 loads landed
  __builtin_amdgcn_s_barrier();

  #pragma unroll 1
  for (int i = 0; i < 16; ++i) {                     // 2 K-tiles / iter, 32 tiles
    const int  t2   = 2 * i + 2, t3 = 2 * i + 3;
    const bool more = (i < 15);
    // tile 2i from buf0
    phase<0, true >(aRd0, bRd0, ko0, ko1, acc, bf,
                    [&] { stage_half(gA, lA1, 2 * i + 1, 1, wid); }, -1);
    phase<1, false>(aRd0, bRd0, ko0, ko1, acc, bf,
                    [&] { if (more) stage_half(gB, lB0, t2, 0, wid); }, -1);
    phase<2, false>(aRd0, bRd0, ko0, ko1, acc, bf,
                    [&] { if (more) stage_half(gB, lB0, t2, 1, wid); }, -1);
    phase<3, false>(aRd0, bRd0, ko0, ko1, acc, bf,
                    [&] { if (more) stage_half(gA, lA0, t2, 0, wid); }, more ? 6 : 0);
    // tile 2i+1 from buf1
    phase<0, true >(aRd1, bRd1, ko0, ko1, acc, bf,
                    [&] { if (more) stage_half(gA, lA0, t2, 1, wid); }, -1);
    phase<1, false>(aRd1, bRd1, ko0, ko1, acc, bf,
                    [&] { if (more) stage_half(gB, lB1, t3, 0, wid); }, -1);
    phase<2, false>(aRd1, bRd1, ko0, ko1, acc, bf,
                    [&] { if (more) stage_half(gB, lB1, t3, 1, wid); }, -1);
    phase<3, false>(aRd1, bRd1, ko0, ko1, acc, bf,
                    [&] { if (more) stage_half(gA, lA1, t3, 0, wid); }, more ? 6 : -1);
  }

  // epilogue: D col = lane&15, row = (lane>>4)*4 + reg
  const int mB = rowBase + wr * 128 + (lane >> 4) * 4;
  const int nB = colBase + wc * 64 + (lane & 15);
  #pragma unroll
  for (int ni = 0; ni < 4; ++ni) {
    float bv = bias[nB + ni * 16];
    #pragma unroll
    for (int mi = 0; mi < 8; ++mi)
      #pragma unroll
      for (int r = 0; r < 4; ++r)
        C[(size_t)(mB + mi * 16 + r) * OUT_DIM + (nB + ni * 16)] = acc[mi][ni][r] + bv;
  }
}

extern "C" void kernel_launch(void* const* d_in, const int* in_sizes, int n_in,
                              void* d_out, int out_size, void* d_ws, size_t ws_size,
                              hipStream_t stream) {
  const float* x    = (const float*)d_in[0];
  const int*   idx  = (const int*)d_in[1];
  const float* lut  = (const float*)d_in[2];
  const float* sA   = (const float*)d_in[3];
  const float* sB   = (const float*)d_in[4];
  const float* mag  = (const float*)d_in[5];
  const float* bias = (const float*)d_in[6];
  float* y = (float*)d_out;

  char* ws = (char*)d_ws;
  float*    c  = (float*)ws;                                            // 16 B
  ushort_t* W  = (ushort_t*)(ws + 256);                                 // 8 MiB
  ushort_t* xb = (ushort_t*)(ws + 256 + (size_t)OUT_DIM * IN_DIM * 2);  // 32 MiB

  coef_kernel<<<1, 256, 0, stream>>>(sA, sB, mag, c);
  prep_kernel<<<8192 + OUT_DIM, 256, 0, stream>>>(x, xb, idx, lut, sA, sB, c, W);
  dim3 g(OUT_DIM / 256, MROWS / 256);
  gemm_kernel<<<g, 512, 0, stream>>>(xb, W, bias, y);
}

// Round 7
// 206.493 us; speedup vs baseline: 1.0670x; 1.0670x over previous
//
#include <hip/hip_runtime.h>

#define IN_DIM  2048   // K
#define OUT_DIM 2048   // N
#define MROWS   8192   // M = B*S
#define RANK    4
#define BK      64

typedef unsigned short ushort_t;
typedef __attribute__((ext_vector_type(8))) short  short8;   // 8 bf16 (4 VGPRs)
typedef __attribute__((ext_vector_type(4))) float  floatx4;  // MFMA acc

__device__ __forceinline__ unsigned short f2bf(float f) {
  union { float f; unsigned int u; } v; v.f = f;
  unsigned int r = v.u + 0x7fffu + ((v.u >> 16) & 1u);  // RNE
  return (unsigned short)(r >> 16);
}

__device__ __forceinline__ void gload16(const ushort_t* g, short* l) {
  __builtin_amdgcn_global_load_lds(
      (const __attribute__((address_space(1))) void*)g,
      (__attribute__((address_space(3))) void*)l, 16, 0, 0);
}

// ---- fused prep (R7): coef_kernel folded in; 2 launches total ----
// blocks [0,8192): cast x->bf16 (unchanged).
// blocks [8192,10240): build W row o. Each W-block computes the rank coefs
// c[r] = softplus(mag_r)/(||A[:,r]||*||B[r,:]||) INLINE (redundantly): 64 KB
// of sA/sB reads per block are the same lines chip-wide -> L2-broadcast-hot
// (~4us aggregate). Wave shfl_xor tree replaces the old serial 256-iter loop.
__global__ void prep_kernel(const float* __restrict__ x, ushort_t* __restrict__ xb,
                            const int* __restrict__ idx, const float* __restrict__ lut,
                            const float* __restrict__ sA, const float* __restrict__ sB,
                            const float* __restrict__ mag, ushort_t* __restrict__ W) {
  int t = threadIdx.x;
  if (blockIdx.x < 8192) {
    size_t i = ((size_t)blockIdx.x * 256 + t) * 8;
    float4 a = *(const float4*)(x + i);
    float4 b = *(const float4*)(x + i + 4);
    uint4 o4;
    o4.x = (unsigned)f2bf(a.x) | ((unsigned)f2bf(a.y) << 16);
    o4.y = (unsigned)f2bf(a.z) | ((unsigned)f2bf(a.w) << 16);
    o4.z = (unsigned)f2bf(b.x) | ((unsigned)f2bf(b.y) << 16);
    o4.w = (unsigned)f2bf(b.z) | ((unsigned)f2bf(b.w) << 16);
    *(uint4*)(xb + i) = o4;
  } else {
    __shared__ float aA[4];
    __shared__ float lutS[16];
    __shared__ float redW[4][8];
    const int o    = blockIdx.x - 8192;
    const int lane = t & 63;
    const int wid  = t >> 6;

    // per-thread partial squared norms
    float sa[4] = {0.f, 0.f, 0.f, 0.f};
    for (int oo = t; oo < OUT_DIM; oo += 256) {
      float4 v = *(const float4*)(sA + oo * 4);
      sa[0] += v.x * v.x; sa[1] += v.y * v.y; sa[2] += v.z * v.z; sa[3] += v.w * v.w;
    }
    float sb[4];
    #pragma unroll
    for (int r = 0; r < 4; ++r) {
      float4 u = *(const float4*)(sB + r * IN_DIM + t * 8);
      float4 v = *(const float4*)(sB + r * IN_DIM + t * 8 + 4);
      sb[r] = u.x*u.x + u.y*u.y + u.z*u.z + u.w*u.w
            + v.x*v.x + v.y*v.y + v.z*v.z + v.w*v.w;
    }
    // wave tree-reduce 8 values, then cross-wave via LDS
    #pragma unroll
    for (int off = 32; off; off >>= 1) {
      #pragma unroll
      for (int q = 0; q < 4; ++q) {
        sa[q] += __shfl_xor(sa[q], off);
        sb[q] += __shfl_xor(sb[q], off);
      }
    }
    if (lane == 0) {
      #pragma unroll
      for (int q = 0; q < 4; ++q) { redW[wid][q] = sa[q]; redW[wid][4 + q] = sb[q]; }
    }
    if (t < 16) lutS[t] = lut[t];
    __syncthreads();
    if (t < 4) {
      float ta = redW[0][t]     + redW[1][t]     + redW[2][t]     + redW[3][t];
      float tb = redW[0][4 + t] + redW[1][4 + t] + redW[2][4 + t] + redW[3][4 + t];
      float g  = log1pf(expf(mag[t])) + 1e-6f;        // softplus + mag_eps
      float na = fmaxf(sqrtf(ta), 1e-6f);
      float nb = fmaxf(sqrtf(tb), 1e-6f);
      aA[t] = fabsf(sA[o * 4 + t]) * (g / (na * nb));
    }
    __syncthreads();

    int i = t * 8;
    const int4* ip4 = (const int4*)(idx + (size_t)o * IN_DIM + i);
    int4 i0 = ip4[0], i1 = ip4[1];
    int ii[8] = {i0.x, i0.y, i0.z, i0.w, i1.x, i1.y, i1.z, i1.w};
    unsigned short u[8];
    #pragma unroll
    for (int j = 0; j < 8; ++j) {
      float s = aA[0] * fabsf(sB[0 * IN_DIM + i + j])
              + aA[1] * fabsf(sB[1 * IN_DIM + i + j])
              + aA[2] * fabsf(sB[2 * IN_DIM + i + j])
              + aA[3] * fabsf(sB[3 * IN_DIM + i + j]);
      u[j] = f2bf(lutS[ii[j]] * s);
    }
    uint4 o4;
    o4.x = (unsigned)u[0] | ((unsigned)u[1] << 16);
    o4.y = (unsigned)u[2] | ((unsigned)u[3] << 16);
    o4.z = (unsigned)u[4] | ((unsigned)u[5] << 16);
    o4.w = (unsigned)u[6] | ((unsigned)u[7] << 16);
    *(uint4*)(W + (size_t)o * IN_DIM + i) = o4;
  }
}

// ============================================================================
// kernel 3: C[M,N] = A[M,K] * W[N,K]^T + bias  -- FROZEN from R6 (best ~79.5us).
// 256x256 tile, BK=64, 8 waves (2x4), 8-phase counted-vmcnt schedule.
// R2: XCD-chunked tile remap (FETCH 135->49 MB, verified).
// R3-R6: four sync-structure variants (fences, read placement, A-pipeline,
//   literal m201 skeleton) ALL NULL at ~1490 cyc/phase, MfmaUtil ~35%.
//   Conclusion: documented template mechanics faithfully ported do not
//   reproduce m201's 824 cyc/phase on this shape at HIP level; gemm lever
//   exhausted pending a regime change (32x32 MFMA shape / multi-block-CU).
// ============================================================================

#define MFMA16(a, b, c) __builtin_amdgcn_mfma_f32_16x16x32_bf16(a, b, c, 0, 0, 0)

// stage one A/B half-tile (h) of K-tile `tile` into `ldsbase` (2 x gload16/thread)
__device__ __forceinline__ void stage_half(const ushort_t* gbase, short* ldsbase,
                                           int tile, int h, int wid) {
  gload16(gbase + (size_t)h * 64 * IN_DIM + (size_t)tile * BK,
          ldsbase + (h * 512 + wid * 64) * 8);
  gload16(gbase + ((size_t)h * 64 + 128) * IN_DIM + (size_t)tile * BK,
          ldsbase + (1024 + h * 512 + wid * 64) * 8);
}

// m201 skeleton: reads -> stage -> [hints] -> barrier -> lgkmcnt(0) -> MFMA -> barrier
template <int MQ, bool FIRST, typename StageFn>
__device__ __forceinline__ void phase(const short* aRd, const short* bRd,
                                      int ko0, int ko1,
                                      floatx4 (&acc)[8][4], short8 (&bf)[8],
                                      StageFn&& stage, int vm) {
  short8 a0k0 = *(const short8*)(aRd + (2 * MQ) * 1024 + ko0);
  short8 a0k1 = *(const short8*)(aRd + (2 * MQ) * 1024 + ko1);
  short8 a1k0 = *(const short8*)(aRd + (2 * MQ + 1) * 1024 + ko0);
  short8 a1k1 = *(const short8*)(aRd + (2 * MQ + 1) * 1024 + ko1);
  if (FIRST) {
    #pragma unroll
    for (int ni = 0; ni < 4; ++ni) {
      bf[ni]     = *(const short8*)(bRd + ni * 1024 + ko0);
      bf[4 + ni] = *(const short8*)(bRd + ni * 1024 + ko1);
    }
  }
  stage();
  if (FIRST)        asm volatile("s_waitcnt lgkmcnt(8)");  // bound pre-barrier DS queue
  if (vm == 6)      asm volatile("s_waitcnt vmcnt(6)");
  else if (vm == 0) asm volatile("s_waitcnt vmcnt(0)");
  __builtin_amdgcn_sched_barrier(0);     // pin reads/stage ABOVE the barrier
  __builtin_amdgcn_s_barrier();
  asm volatile("s_waitcnt lgkmcnt(0)");
  __builtin_amdgcn_sched_barrier(0);     // rule #18: keep MFMA below the wait
  __builtin_amdgcn_s_setprio(1);
  #pragma unroll
  for (int ni = 0; ni < 4; ++ni)
    acc[2 * MQ    ][ni] = MFMA16(a0k0, bf[ni],     acc[2 * MQ    ][ni]);
  #pragma unroll
  for (int ni = 0; ni < 4; ++ni)
    acc[2 * MQ + 1][ni] = MFMA16(a1k0, bf[ni],     acc[2 * MQ + 1][ni]);
  #pragma unroll
  for (int ni = 0; ni < 4; ++ni)
    acc[2 * MQ    ][ni] = MFMA16(a0k1, bf[4 + ni], acc[2 * MQ    ][ni]);
  #pragma unroll
  for (int ni = 0; ni < 4; ++ni)
    acc[2 * MQ + 1][ni] = MFMA16(a1k1, bf[4 + ni], acc[2 * MQ + 1][ni]);
  __builtin_amdgcn_s_setprio(0);
  __builtin_amdgcn_s_barrier();
}

__global__ __launch_bounds__(512, 2) void gemm_kernel(const ushort_t* __restrict__ A,
                                                      const ushort_t* __restrict__ W,
                                                      const float* __restrict__ bias,
                                                      float* __restrict__ C) {
  __shared__ short lA0[16384];   // 256x64 bf16 = 32 KiB each, 128 KiB total
  __shared__ short lB0[16384];
  __shared__ short lA1[16384];
  __shared__ short lB1[16384];

  const int t    = threadIdx.x;
  const int lane = t & 63;
  const int wid  = t >> 6;       // 8 waves: 2 (M) x 4 (N)
  const int wr   = wid >> 2;
  const int wc   = wid & 3;

  // XCD-chunked tile remap (R2). flat id in hw dispatch order:
  const int flat  = blockIdx.y * 8 + blockIdx.x;   // x-fastest
  const int xcd   = flat & 7;                      // round-robin XCD assignment
  const int slot  = flat >> 3;                     // 0..31: CU slot within XCD
  const int tileY = (xcd >> 1) * 8 + (slot >> 2);  // 8 consecutive y-tiles / XCD
  const int tileX = (xcd & 1) * 4 + (slot & 3);    // 4 consecutive x-tiles / XCD
  const int rowBase = tileY * 256;
  const int colBase = tileX * 256;

  // staging source: thread covers row srcRow of each 64-row quadrant, chunk pre-swizzled
  const int srcRow   = wid * 8 + (lane >> 3);
  const int srcChunk = (lane & 7) ^ (lane >> 3);   // slot ^ (row&7)
  const ushort_t* gA = A + (size_t)(rowBase + srcRow) * IN_DIM + srcChunk * 8;
  const ushort_t* gB = W + (size_t)(colBase + srcRow) * IN_DIM + srcChunk * 8;

  // fragment-read addressing
  const int rA  = lane & 15;
  const int kh  = lane >> 4;
  const int sw  = rA & 7;
  const int ko0 = ((kh)     ^ sw) * 8;   // kk=0 chunk, swizzled, in shorts
  const int ko1 = ((4 + kh) ^ sw) * 8;   // kk=1
  const short* aRd0 = lA0 + (wr * 128 + rA) * 64;
  const short* bRd0 = lB0 + (wc * 64  + rA) * 64;
  const short* aRd1 = lA1 + (wr * 128 + rA) * 64;
  const short* bRd1 = lB1 + (wc * 64  + rA) * 64;

  floatx4 acc[8][4];
  #pragma unroll
  for (int i = 0; i < 8; ++i)
    #pragma unroll
    for (int j = 0; j < 4; ++j) acc[i][j] = (floatx4){0.f, 0.f, 0.f, 0.f};
  short8 bf[8];

  // prologue: tile0 complete (8 loads), then tile1 Bh0,Bh1,Ah0 (6 loads)
  stage_half(gA, lA0, 0, 0, wid);
  stage_half(gA, lA0, 0, 1, wid);
  stage_half(gB, lB0, 0, 0, wid);
  stage_half(gB, lB0, 0, 1, wid);
  stage_half(gB, lB1, 1, 0, wid);
  stage_half(gB, lB1, 1, 1, wid);
  stage_half(gA, lA1, 1, 0, wid);
  asm volatile("s_waitcnt vmcnt(6)");   // tile0's 8 loads landed
  __builtin_amdgcn_s_barrier();

  #pragma unroll 1
  for (int i = 0; i < 16; ++i) {                     // 2 K-tiles / iter, 32 tiles
    const int  t2   = 2 * i + 2, t3 = 2 * i + 3;
    const bool more = (i < 15);
    // tile 2i from buf0
    phase<0, true >(aRd0, bRd0, ko0, ko1, acc, bf,
                    [&] { stage_half(gA, lA1, 2 * i + 1, 1, wid); }, -1);
    phase<1, false>(aRd0, bRd0, ko0, ko1, acc, bf,
                    [&] { if (more) stage_half(gB, lB0, t2, 0, wid); }, -1);
    phase<2, false>(aRd0, bRd0, ko0, ko1, acc, bf,
                    [&] { if (more) stage_half(gB, lB0, t2, 1, wid); }, -1);
    phase<3, false>(aRd0, bRd0, ko0, ko1, acc, bf,
                    [&] { if (more) stage_half(gA, lA0, t2, 0, wid); }, more ? 6 : 0);
    // tile 2i+1 from buf1
    phase<0, true >(aRd1, bRd1, ko0, ko1, acc, bf,
                    [&] { if (more) stage_half(gA, lA0, t2, 1, wid); }, -1);
    phase<1, false>(aRd1, bRd1, ko0, ko1, acc, bf,
                    [&] { if (more) stage_half(gB, lB1, t3, 0, wid); }, -1);
    phase<2, false>(aRd1, bRd1, ko0, ko1, acc, bf,
                    [&] { if (more) stage_half(gB, lB1, t3, 1, wid); }, -1);
    phase<3, false>(aRd1, bRd1, ko0, ko1, acc, bf,
                    [&] { if (more) stage_half(gA, lA1, t3, 0, wid); }, more ? 6 : -1);
  }

  // epilogue: D col = lane&15, row = (lane>>4)*4 + reg
  const int mB = rowBase + wr * 128 + (lane >> 4) * 4;
  const int nB = colBase + wc * 64 + (lane & 15);
  #pragma unroll
  for (int ni = 0; ni < 4; ++ni) {
    float bv = bias[nB + ni * 16];
    #pragma unroll
    for (int mi = 0; mi < 8; ++mi)
      #pragma unroll
      for (int r = 0; r < 4; ++r)
        C[(size_t)(mB + mi * 16 + r) * OUT_DIM + (nB + ni * 16)] = acc[mi][ni][r] + bv;
  }
}

extern "C" void kernel_launch(void* const* d_in, const int* in_sizes, int n_in,
                              void* d_out, int out_size, void* d_ws, size_t ws_size,
                              hipStream_t stream) {
  const float* x    = (const float*)d_in[0];
  const int*   idx  = (const int*)d_in[1];
  const float* lut  = (const float*)d_in[2];
  const float* sA   = (const float*)d_in[3];
  const float* sB   = (const float*)d_in[4];
  const float* mag  = (const float*)d_in[5];
  const float* bias = (const float*)d_in[6];
  float* y = (float*)d_out;

  char* ws = (char*)d_ws;
  ushort_t* W  = (ushort_t*)(ws + 256);                                 // 8 MiB
  ushort_t* xb = (ushort_t*)(ws + 256 + (size_t)OUT_DIM * IN_DIM * 2);  // 32 MiB

  prep_kernel<<<8192 + OUT_DIM, 256, 0, stream>>>(x, xb, idx, lut, sA, sB, mag, W);
  dim3 g(OUT_DIM / 256, MROWS / 256);
  gemm_kernel<<<g, 512, 0, stream>>>(xb, W, bias, y);
}

// Round 8
// 206.131 us; speedup vs baseline: 1.0688x; 1.0018x over previous
//
#include <hip/hip_runtime.h>

#define IN_DIM  2048   // K
#define OUT_DIM 2048   // N
#define MROWS   8192   // M = B*S
#define RANK    4
#define BK      64

typedef unsigned short ushort_t;
typedef __attribute__((ext_vector_type(8))) short  short8;   // 8 bf16 (4 VGPRs)
typedef __attribute__((ext_vector_type(4))) float  floatx4;  // MFMA acc

__device__ __forceinline__ unsigned short f2bf(float f) {
  union { float f; unsigned int u; } v; v.f = f;
  unsigned int r = v.u + 0x7fffu + ((v.u >> 16) & 1u);  // RNE
  return (unsigned short)(r >> 16);
}

__device__ __forceinline__ void gload16(const ushort_t* g, short* l) {
  __builtin_amdgcn_global_load_lds(
      (const __attribute__((address_space(1))) void*)g,
      (__attribute__((address_space(3))) void*)l, 16, 0, 0);
}

// ---- fused prep (R7, verified +14us): 2 launches total ----
__global__ void prep_kernel(const float* __restrict__ x, ushort_t* __restrict__ xb,
                            const int* __restrict__ idx, const float* __restrict__ lut,
                            const float* __restrict__ sA, const float* __restrict__ sB,
                            const float* __restrict__ mag, ushort_t* __restrict__ W) {
  int t = threadIdx.x;
  if (blockIdx.x < 8192) {
    size_t i = ((size_t)blockIdx.x * 256 + t) * 8;
    float4 a = *(const float4*)(x + i);
    float4 b = *(const float4*)(x + i + 4);
    uint4 o4;
    o4.x = (unsigned)f2bf(a.x) | ((unsigned)f2bf(a.y) << 16);
    o4.y = (unsigned)f2bf(a.z) | ((unsigned)f2bf(a.w) << 16);
    o4.z = (unsigned)f2bf(b.x) | ((unsigned)f2bf(b.y) << 16);
    o4.w = (unsigned)f2bf(b.z) | ((unsigned)f2bf(b.w) << 16);
    *(uint4*)(xb + i) = o4;
  } else {
    __shared__ float aA[4];
    __shared__ float lutS[16];
    __shared__ float redW[4][8];
    const int o    = blockIdx.x - 8192;
    const int lane = t & 63;
    const int wid  = t >> 6;

    float sa[4] = {0.f, 0.f, 0.f, 0.f};
    for (int oo = t; oo < OUT_DIM; oo += 256) {
      float4 v = *(const float4*)(sA + oo * 4);
      sa[0] += v.x * v.x; sa[1] += v.y * v.y; sa[2] += v.z * v.z; sa[3] += v.w * v.w;
    }
    float sb[4];
    #pragma unroll
    for (int r = 0; r < 4; ++r) {
      float4 u = *(const float4*)(sB + r * IN_DIM + t * 8);
      float4 v = *(const float4*)(sB + r * IN_DIM + t * 8 + 4);
      sb[r] = u.x*u.x + u.y*u.y + u.z*u.z + u.w*u.w
            + v.x*v.x + v.y*v.y + v.z*v.z + v.w*v.w;
    }
    #pragma unroll
    for (int off = 32; off; off >>= 1) {
      #pragma unroll
      for (int q = 0; q < 4; ++q) {
        sa[q] += __shfl_xor(sa[q], off);
        sb[q] += __shfl_xor(sb[q], off);
      }
    }
    if (lane == 0) {
      #pragma unroll
      for (int q = 0; q < 4; ++q) { redW[wid][q] = sa[q]; redW[wid][4 + q] = sb[q]; }
    }
    if (t < 16) lutS[t] = lut[t];
    __syncthreads();
    if (t < 4) {
      float ta = redW[0][t]     + redW[1][t]     + redW[2][t]     + redW[3][t];
      float tb = redW[0][4 + t] + redW[1][4 + t] + redW[2][4 + t] + redW[3][4 + t];
      float g  = log1pf(expf(mag[t])) + 1e-6f;        // softplus + mag_eps
      float na = fmaxf(sqrtf(ta), 1e-6f);
      float nb = fmaxf(sqrtf(tb), 1e-6f);
      aA[t] = fabsf(sA[o * 4 + t]) * (g / (na * nb));
    }
    __syncthreads();

    int i = t * 8;
    const int4* ip4 = (const int4*)(idx + (size_t)o * IN_DIM + i);
    int4 i0 = ip4[0], i1 = ip4[1];
    int ii[8] = {i0.x, i0.y, i0.z, i0.w, i1.x, i1.y, i1.z, i1.w};
    unsigned short u[8];
    #pragma unroll
    for (int j = 0; j < 8; ++j) {
      float s = aA[0] * fabsf(sB[0 * IN_DIM + i + j])
              + aA[1] * fabsf(sB[1 * IN_DIM + i + j])
              + aA[2] * fabsf(sB[2 * IN_DIM + i + j])
              + aA[3] * fabsf(sB[3 * IN_DIM + i + j]);
      u[j] = f2bf(lutS[ii[j]] * s);
    }
    uint4 o4;
    o4.x = (unsigned)u[0] | ((unsigned)u[1] << 16);
    o4.y = (unsigned)u[2] | ((unsigned)u[3] << 16);
    o4.z = (unsigned)u[4] | ((unsigned)u[5] << 16);
    o4.w = (unsigned)u[6] | ((unsigned)u[7] << 16);
    *(uint4*)(W + (size_t)o * IN_DIM + i) = o4;
  }
}

// ============================================================================
// kernel 3: C[M,N] = A[M,K] * W[N,K]^T + bias
// 256x256 tile, BK=64, 8 waves (2x4), 8-phase counted-vmcnt schedule.
// R2: XCD-chunked tile remap (FETCH 135->49 MB, verified).
// R3-R6: four sync variants NULL at ~1490 cyc/phase (ideal model: 620 MFMA +
//   ~200 LDS = 824, m201-consistent). Remaining +670 attributed to per-phase
//   barrier SKEW: 16 DMA ops/CU serviced serially (~550 cy); slowest wave's
//   vmcnt drags each barrier, paid TWICE with 2 barriers/phase.
// R8 (this round): ONE barrier per phase (drop the post-MFMA barrier).
//   Safety: reads+stage issue PRE-barrier, vmcnt PRE-barrier =>
//   BAR1(p) alone gives (i) all waves' phase-p reads issued before any wave's
//   phase-p+1 stage (stage(p+1) is post-BAR1(p) in program order);
//   (ii) all waves' staged loads for the consumed buffer retired pre-barrier.
//   Residual window (in-flight ds_read vs incoming DMA write) has >=700 cy
//   deterministic margin: reader's lgkmcnt(0) ~100cy post-BAR1; overwriting
//   DMA lands >=900cy post-BAR1 (behind issuer's lgkm0+MFMA cluster+DMA lat).
//   Violation would fail verification loudly (absmax), not silently.
// Stage plan per iter i (tiles u=2i buf0, u+1 buf1):
//   P1 lA1.Ah1(u+1)   P2 lB0.Bh0(u+2)  P3 lB0.Bh1(u+2)  P4 lA0.Ah0(u+2) vm6
//   P5 lA0.Ah1(u+2)   P6 lB1.Bh0(u+3)  P7 lB1.Bh1(u+3)  P8 lA1.Ah0(u+3) vm6
// ============================================================================

#define MFMA16(a, b, c) __builtin_amdgcn_mfma_f32_16x16x32_bf16(a, b, c, 0, 0, 0)

__device__ __forceinline__ void stage_half(const ushort_t* gbase, short* ldsbase,
                                           int tile, int h, int wid) {
  gload16(gbase + (size_t)h * 64 * IN_DIM + (size_t)tile * BK,
          ldsbase + (h * 512 + wid * 64) * 8);
  gload16(gbase + ((size_t)h * 64 + 128) * IN_DIM + (size_t)tile * BK,
          ldsbase + (1024 + h * 512 + wid * 64) * 8);
}

// single-barrier phase: reads -> stage -> [hints] -> BAR -> lgkm0 -> MFMA
template <int MQ, bool FIRST, typename StageFn>
__device__ __forceinline__ void phase(const short* aRd, const short* bRd,
                                      int ko0, int ko1,
                                      floatx4 (&acc)[8][4], short8 (&bf)[8],
                                      StageFn&& stage, int vm) {
  short8 a0k0 = *(const short8*)(aRd + (2 * MQ) * 1024 + ko0);
  short8 a0k1 = *(const short8*)(aRd + (2 * MQ) * 1024 + ko1);
  short8 a1k0 = *(const short8*)(aRd + (2 * MQ + 1) * 1024 + ko0);
  short8 a1k1 = *(const short8*)(aRd + (2 * MQ + 1) * 1024 + ko1);
  if (FIRST) {
    #pragma unroll
    for (int ni = 0; ni < 4; ++ni) {
      bf[ni]     = *(const short8*)(bRd + ni * 1024 + ko0);
      bf[4 + ni] = *(const short8*)(bRd + ni * 1024 + ko1);
    }
  }
  stage();
  if (FIRST)        asm volatile("s_waitcnt lgkmcnt(8)");  // bound pre-barrier DS queue
  if (vm == 6)      asm volatile("s_waitcnt vmcnt(6)");
  else if (vm == 0) asm volatile("s_waitcnt vmcnt(0)");
  __builtin_amdgcn_sched_barrier(0);     // pin reads/stage ABOVE the barrier
  __builtin_amdgcn_s_barrier();
  asm volatile("s_waitcnt lgkmcnt(0)");
  __builtin_amdgcn_sched_barrier(0);     // rule #18: keep MFMA below the wait
  __builtin_amdgcn_s_setprio(1);
  #pragma unroll
  for (int ni = 0; ni < 4; ++ni)
    acc[2 * MQ    ][ni] = MFMA16(a0k0, bf[ni],     acc[2 * MQ    ][ni]);
  #pragma unroll
  for (int ni = 0; ni < 4; ++ni)
    acc[2 * MQ + 1][ni] = MFMA16(a1k0, bf[ni],     acc[2 * MQ + 1][ni]);
  #pragma unroll
  for (int ni = 0; ni < 4; ++ni)
    acc[2 * MQ    ][ni] = MFMA16(a0k1, bf[4 + ni], acc[2 * MQ    ][ni]);
  #pragma unroll
  for (int ni = 0; ni < 4; ++ni)
    acc[2 * MQ + 1][ni] = MFMA16(a1k1, bf[4 + ni], acc[2 * MQ + 1][ni]);
  __builtin_amdgcn_s_setprio(0);
  // no trailing barrier (R8): next phase's BAR provides the ordering
}

__global__ __launch_bounds__(512, 2) void gemm_kernel(const ushort_t* __restrict__ A,
                                                      const ushort_t* __restrict__ W,
                                                      const float* __restrict__ bias,
                                                      float* __restrict__ C) {
  __shared__ short lA0[16384];   // 256x64 bf16 = 32 KiB each, 128 KiB total
  __shared__ short lB0[16384];
  __shared__ short lA1[16384];
  __shared__ short lB1[16384];

  const int t    = threadIdx.x;
  const int lane = t & 63;
  const int wid  = t >> 6;       // 8 waves: 2 (M) x 4 (N)
  const int wr   = wid >> 2;
  const int wc   = wid & 3;

  // XCD-chunked tile remap (R2). flat id in hw dispatch order:
  const int flat  = blockIdx.y * 8 + blockIdx.x;   // x-fastest
  const int xcd   = flat & 7;                      // round-robin XCD assignment
  const int slot  = flat >> 3;                     // 0..31: CU slot within XCD
  const int tileY = (xcd >> 1) * 8 + (slot >> 2);  // 8 consecutive y-tiles / XCD
  const int tileX = (xcd & 1) * 4 + (slot & 3);    // 4 consecutive x-tiles / XCD
  const int rowBase = tileY * 256;
  const int colBase = tileX * 256;

  // staging source: thread covers row srcRow of each 64-row quadrant, chunk pre-swizzled
  const int srcRow   = wid * 8 + (lane >> 3);
  const int srcChunk = (lane & 7) ^ (lane >> 3);   // slot ^ (row&7)
  const ushort_t* gA = A + (size_t)(rowBase + srcRow) * IN_DIM + srcChunk * 8;
  const ushort_t* gB = W + (size_t)(colBase + srcRow) * IN_DIM + srcChunk * 8;

  // fragment-read addressing
  const int rA  = lane & 15;
  const int kh  = lane >> 4;
  const int sw  = rA & 7;
  const int ko0 = ((kh)     ^ sw) * 8;   // kk=0 chunk, swizzled, in shorts
  const int ko1 = ((4 + kh) ^ sw) * 8;   // kk=1
  const short* aRd0 = lA0 + (wr * 128 + rA) * 64;
  const short* bRd0 = lB0 + (wc * 64  + rA) * 64;
  const short* aRd1 = lA1 + (wr * 128 + rA) * 64;
  const short* bRd1 = lB1 + (wc * 64  + rA) * 64;

  floatx4 acc[8][4];
  #pragma unroll
  for (int i = 0; i < 8; ++i)
    #pragma unroll
    for (int j = 0; j < 4; ++j) acc[i][j] = (floatx4){0.f, 0.f, 0.f, 0.f};
  short8 bf[8];

  // prologue: tile0 complete (8 loads), then tile1 Bh0,Bh1,Ah0 (6 loads)
  stage_half(gA, lA0, 0, 0, wid);
  stage_half(gA, lA0, 0, 1, wid);
  stage_half(gB, lB0, 0, 0, wid);
  stage_half(gB, lB0, 0, 1, wid);
  stage_half(gB, lB1, 1, 0, wid);
  stage_half(gB, lB1, 1, 1, wid);
  stage_half(gA, lA1, 1, 0, wid);
  asm volatile("s_waitcnt vmcnt(6)");   // tile0's 8 loads landed
  __builtin_amdgcn_s_barrier();

  #pragma unroll 1
  for (int i = 0; i < 16; ++i) {                     // 2 K-tiles / iter, 32 tiles
    const int  t2   = 2 * i + 2, t3 = 2 * i + 3;
    const bool more = (i < 15);
    // tile 2i from buf0
    phase<0, true >(aRd0, bRd0, ko0, ko1, acc, bf,
                    [&] { stage_half(gA, lA1, 2 * i + 1, 1, wid); }, -1);
    phase<1, false>(aRd0, bRd0, ko0, ko1, acc, bf,
                    [&] { if (more) stage_half(gB, lB0, t2, 0, wid); }, -1);
    phase<2, false>(aRd0, bRd0, ko0, ko1, acc, bf,
                    [&] { if (more) stage_half(gB, lB0, t2, 1, wid); }, -1);
    phase<3, false>(aRd0, bRd0, ko0, ko1, acc, bf,
                    [&] { if (more) stage_half(gA, lA0, t2, 0, wid); }, more ? 6 : 0);
    // tile 2i+1 from buf1
    phase<0, true >(aRd1, bRd1, ko0, ko1, acc, bf,
                    [&] { if (more) stage_half(gA, lA0, t2, 1, wid); }, -1);
    phase<1, false>(aRd1, bRd1, ko0, ko1, acc, bf,
                    [&] { if (more) stage_half(gB, lB1, t3, 0, wid); }, -1);
    phase<2, false>(aRd1, bRd1, ko0, ko1, acc, bf,
                    [&] { if (more) stage_half(gB, lB1, t3, 1, wid); }, -1);
    phase<3, false>(aRd1, bRd1, ko0, ko1, acc, bf,
                    [&] { if (more) stage_half(gA, lA1, t3, 0, wid); }, more ? 6 : -1);
  }

  // epilogue: D col = lane&15, row = (lane>>4)*4 + reg (regs only, no barrier needed)
  const int mB = rowBase + wr * 128 + (lane >> 4) * 4;
  const int nB = colBase + wc * 64 + (lane & 15);
  #pragma unroll
  for (int ni = 0; ni < 4; ++ni) {
    float bv = bias[nB + ni * 16];
    #pragma unroll
    for (int mi = 0; mi < 8; ++mi)
      #pragma unroll
      for (int r = 0; r < 4; ++r)
        C[(size_t)(mB + mi * 16 + r) * OUT_DIM + (nB + ni * 16)] = acc[mi][ni][r] + bv;
  }
}

extern "C" void kernel_launch(void* const* d_in, const int* in_sizes, int n_in,
                              void* d_out, int out_size, void* d_ws, size_t ws_size,
                              hipStream_t stream) {
  const float* x    = (const float*)d_in[0];
  const int*   idx  = (const int*)d_in[1];
  const float* lut  = (const float*)d_in[2];
  const float* sA   = (const float*)d_in[3];
  const float* sB   = (const float*)d_in[4];
  const float* mag  = (const float*)d_in[5];
  const float* bias = (const float*)d_in[6];
  float* y = (float*)d_out;

  char* ws = (char*)d_ws;
  ushort_t* W  = (ushort_t*)(ws + 256);                                 // 8 MiB
  ushort_t* xb = (ushort_t*)(ws + 256 + (size_t)OUT_DIM * IN_DIM * 2);  // 32 MiB

  prep_kernel<<<8192 + OUT_DIM, 256, 0, stream>>>(x, xb, idx, lut, sA, sB, mag, W);
  dim3 g(OUT_DIM / 256, MROWS / 256);
  gemm_kernel<<<g, 512, 0, stream>>>(xb, W, bias, y);
}

// Round 9
// 204.795 us; speedup vs baseline: 1.0758x; 1.0065x over previous
//
#include <hip/hip_runtime.h>

#define IN_DIM  2048   // K
#define OUT_DIM 2048   // N
#define MROWS   8192   // M = B*S
#define RANK    4
#define BK      64

typedef unsigned short ushort_t;
typedef __attribute__((ext_vector_type(8))) short  short8;   // 8 bf16 (4 VGPRs)
typedef __attribute__((ext_vector_type(4))) float  floatx4;  // MFMA acc

__device__ __forceinline__ unsigned short f2bf(float f) {
  union { float f; unsigned int u; } v; v.f = f;
  unsigned int r = v.u + 0x7fffu + ((v.u >> 16) & 1u);  // RNE
  return (unsigned short)(r >> 16);
}

__device__ __forceinline__ void gload16(const ushort_t* g, short* l) {
  __builtin_amdgcn_global_load_lds(
      (const __attribute__((address_space(1))) void*)g,
      (__attribute__((address_space(3))) void*)l, 16, 0, 0);
}

// ---- fused prep (R7, verified +14us): 2 launches total ----
__global__ void prep_kernel(const float* __restrict__ x, ushort_t* __restrict__ xb,
                            const int* __restrict__ idx, const float* __restrict__ lut,
                            const float* __restrict__ sA, const float* __restrict__ sB,
                            const float* __restrict__ mag, ushort_t* __restrict__ W) {
  int t = threadIdx.x;
  if (blockIdx.x < 8192) {
    size_t i = ((size_t)blockIdx.x * 256 + t) * 8;
    float4 a = *(const float4*)(x + i);
    float4 b = *(const float4*)(x + i + 4);
    uint4 o4;
    o4.x = (unsigned)f2bf(a.x) | ((unsigned)f2bf(a.y) << 16);
    o4.y = (unsigned)f2bf(a.z) | ((unsigned)f2bf(a.w) << 16);
    o4.z = (unsigned)f2bf(b.x) | ((unsigned)f2bf(b.y) << 16);
    o4.w = (unsigned)f2bf(b.z) | ((unsigned)f2bf(b.w) << 16);
    *(uint4*)(xb + i) = o4;
  } else {
    __shared__ float aA[4];
    __shared__ float lutS[16];
    __shared__ float redW[4][8];
    const int o    = blockIdx.x - 8192;
    const int lane = t & 63;
    const int wid  = t >> 6;

    float sa[4] = {0.f, 0.f, 0.f, 0.f};
    for (int oo = t; oo < OUT_DIM; oo += 256) {
      float4 v = *(const float4*)(sA + oo * 4);
      sa[0] += v.x * v.x; sa[1] += v.y * v.y; sa[2] += v.z * v.z; sa[3] += v.w * v.w;
    }
    float sb[4];
    #pragma unroll
    for (int r = 0; r < 4; ++r) {
      float4 u = *(const float4*)(sB + r * IN_DIM + t * 8);
      float4 v = *(const float4*)(sB + r * IN_DIM + t * 8 + 4);
      sb[r] = u.x*u.x + u.y*u.y + u.z*u.z + u.w*u.w
            + v.x*v.x + v.y*v.y + v.z*v.z + v.w*v.w;
    }
    #pragma unroll
    for (int off = 32; off; off >>= 1) {
      #pragma unroll
      for (int q = 0; q < 4; ++q) {
        sa[q] += __shfl_xor(sa[q], off);
        sb[q] += __shfl_xor(sb[q], off);
      }
    }
    if (lane == 0) {
      #pragma unroll
      for (int q = 0; q < 4; ++q) { redW[wid][q] = sa[q]; redW[wid][4 + q] = sb[q]; }
    }
    if (t < 16) lutS[t] = lut[t];
    __syncthreads();
    if (t < 4) {
      float ta = redW[0][t]     + redW[1][t]     + redW[2][t]     + redW[3][t];
      float tb = redW[0][4 + t] + redW[1][4 + t] + redW[2][4 + t] + redW[3][4 + t];
      float g  = log1pf(expf(mag[t])) + 1e-6f;        // softplus + mag_eps
      float na = fmaxf(sqrtf(ta), 1e-6f);
      float nb = fmaxf(sqrtf(tb), 1e-6f);
      aA[t] = fabsf(sA[o * 4 + t]) * (g / (na * nb));
    }
    __syncthreads();

    int i = t * 8;
    const int4* ip4 = (const int4*)(idx + (size_t)o * IN_DIM + i);
    int4 i0 = ip4[0], i1 = ip4[1];
    int ii[8] = {i0.x, i0.y, i0.z, i0.w, i1.x, i1.y, i1.z, i1.w};
    unsigned short u[8];
    #pragma unroll
    for (int j = 0; j < 8; ++j) {
      float s = aA[0] * fabsf(sB[0 * IN_DIM + i + j])
              + aA[1] * fabsf(sB[1 * IN_DIM + i + j])
              + aA[2] * fabsf(sB[2 * IN_DIM + i + j])
              + aA[3] * fabsf(sB[3 * IN_DIM + i + j]);
      u[j] = f2bf(lutS[ii[j]] * s);
    }
    uint4 o4;
    o4.x = (unsigned)u[0] | ((unsigned)u[1] << 16);
    o4.y = (unsigned)u[2] | ((unsigned)u[3] << 16);
    o4.z = (unsigned)u[4] | ((unsigned)u[5] << 16);
    o4.w = (unsigned)u[6] | ((unsigned)u[7] << 16);
    *(uint4*)(W + (size_t)o * IN_DIM + i) = o4;
  }
}

// ============================================================================
// kernel 3: C[M,N] = A[M,K] * W[N,K]^T + bias
// 256x256 tile, BK=64, 8 waves (2x4), 8-phase counted-vmcnt, single barrier.
// R2: XCD-chunked tile remap (FETCH 135->49 MB, verified).
// R8: one barrier/phase (verified +5us; per-barrier cost ~100cy).
// R9 (this round): remove the forced lgkmcnt(0) drain + sched_barrier pin
//   between frag reads and MFMA. Accounting that closed the books: LDS read
//   service 48 b128/CU/phase @85B/cy ~= 580cy; matrix pipe 620cy; the explicit
//   lgkmcnt(0)+sched_barrier made them DISJOINT -> 1300-1400cy measured.
//   rule #18 applies to inline-asm ds_reads; ours are IR loads -- the compiler
//   emits counted lgkmcnt per MFMA operand group (m97 asm evidence), so MFMA
//   group 1 starts after its 5 reads and the ~7 tail reads land under MFMA.
//   Phase: stage -> vmcnt -> SB(0) -> s_barrier -> SB(0) -> reads (bf first)
//   -> setprio(1) -> MFMA (counted waits) -> setprio(0).
//   Cross-phase ordering identical to verified R8: the SB(0) pair around the
//   barrier prevents any hoist above it (protects vmcnt RAW guarantee).
//   WAR margin: overwriting DMA lands >=1100cy after the barrier preceding
//   the victim reads; reads retire <=~700cy after it.
// Stage plan per iter i (tiles u=2i buf0, u+1 buf1):
//   P1 lA1.Ah1(u+1)   P2 lB0.Bh0(u+2)  P3 lB0.Bh1(u+2)  P4 lA0.Ah0(u+2) vm6
//   P5 lA0.Ah1(u+2)   P6 lB1.Bh0(u+3)  P7 lB1.Bh1(u+3)  P8 lA1.Ah0(u+3) vm6
// vmcnt(6)@P4 retires prev P6..P8+P1 -> buf1 landed; @P8 retires P2..P5 ->
// buf0' landed. Last iter: P4 vm0, stages skipped.
// ============================================================================

#define MFMA16(a, b, c) __builtin_amdgcn_mfma_f32_16x16x32_bf16(a, b, c, 0, 0, 0)

__device__ __forceinline__ void stage_half(const ushort_t* gbase, short* ldsbase,
                                           int tile, int h, int wid) {
  gload16(gbase + (size_t)h * 64 * IN_DIM + (size_t)tile * BK,
          ldsbase + (h * 512 + wid * 64) * 8);
  gload16(gbase + ((size_t)h * 64 + 128) * IN_DIM + (size_t)tile * BK,
          ldsbase + (1024 + h * 512 + wid * 64) * 8);
}

// single-barrier phase, compiler-counted lgkm waits (R9)
template <int MQ, bool FIRST, typename StageFn>
__device__ __forceinline__ void phase(const short* aRd, const short* bRd,
                                      int ko0, int ko1,
                                      floatx4 (&acc)[8][4], short8 (&bf)[8],
                                      StageFn&& stage, int vm) {
  stage();
  if (vm == 6)      asm volatile("s_waitcnt vmcnt(6)");
  else if (vm == 0) asm volatile("s_waitcnt vmcnt(0)");
  __builtin_amdgcn_sched_barrier(0);     // stage+vmcnt stay above the barrier
  __builtin_amdgcn_s_barrier();
  __builtin_amdgcn_sched_barrier(0);     // nothing below hoists above the barrier
  // frag reads: group-1 operands first so its MFMAs can issue after 5 reads
  if (FIRST) {
    #pragma unroll
    for (int ni = 0; ni < 4; ++ni)
      bf[ni] = *(const short8*)(bRd + ni * 1024 + ko0);
  }
  short8 a0k0 = *(const short8*)(aRd + (2 * MQ) * 1024 + ko0);
  short8 a1k0 = *(const short8*)(aRd + (2 * MQ + 1) * 1024 + ko0);
  if (FIRST) {
    #pragma unroll
    for (int ni = 0; ni < 4; ++ni)
      bf[4 + ni] = *(const short8*)(bRd + ni * 1024 + ko1);
  }
  short8 a0k1 = *(const short8*)(aRd + (2 * MQ) * 1024 + ko1);
  short8 a1k1 = *(const short8*)(aRd + (2 * MQ + 1) * 1024 + ko1);
  __builtin_amdgcn_s_setprio(1);
  // NO sched_barrier / lgkmcnt(0) here: compiler emits counted lgkmcnt per
  // MFMA group; tail reads complete under the MFMA cluster.
  #pragma unroll
  for (int ni = 0; ni < 4; ++ni)
    acc[2 * MQ    ][ni] = MFMA16(a0k0, bf[ni],     acc[2 * MQ    ][ni]);
  #pragma unroll
  for (int ni = 0; ni < 4; ++ni)
    acc[2 * MQ + 1][ni] = MFMA16(a1k0, bf[ni],     acc[2 * MQ + 1][ni]);
  #pragma unroll
  for (int ni = 0; ni < 4; ++ni)
    acc[2 * MQ    ][ni] = MFMA16(a0k1, bf[4 + ni], acc[2 * MQ    ][ni]);
  #pragma unroll
  for (int ni = 0; ni < 4; ++ni)
    acc[2 * MQ + 1][ni] = MFMA16(a1k1, bf[4 + ni], acc[2 * MQ + 1][ni]);
  __builtin_amdgcn_s_setprio(0);
}

__global__ __launch_bounds__(512, 2) void gemm_kernel(const ushort_t* __restrict__ A,
                                                      const ushort_t* __restrict__ W,
                                                      const float* __restrict__ bias,
                                                      float* __restrict__ C) {
  __shared__ short lA0[16384];   // 256x64 bf16 = 32 KiB each, 128 KiB total
  __shared__ short lB0[16384];
  __shared__ short lA1[16384];
  __shared__ short lB1[16384];

  const int t    = threadIdx.x;
  const int lane = t & 63;
  const int wid  = t >> 6;       // 8 waves: 2 (M) x 4 (N)
  const int wr   = wid >> 2;
  const int wc   = wid & 3;

  // XCD-chunked tile remap (R2). flat id in hw dispatch order:
  const int flat  = blockIdx.y * 8 + blockIdx.x;   // x-fastest
  const int xcd   = flat & 7;                      // round-robin XCD assignment
  const int slot  = flat >> 3;                     // 0..31: CU slot within XCD
  const int tileY = (xcd >> 1) * 8 + (slot >> 2);  // 8 consecutive y-tiles / XCD
  const int tileX = (xcd & 1) * 4 + (slot & 3);    // 4 consecutive x-tiles / XCD
  const int rowBase = tileY * 256;
  const int colBase = tileX * 256;

  // staging source: thread covers row srcRow of each 64-row quadrant, chunk pre-swizzled
  const int srcRow   = wid * 8 + (lane >> 3);
  const int srcChunk = (lane & 7) ^ (lane >> 3);   // slot ^ (row&7)
  const ushort_t* gA = A + (size_t)(rowBase + srcRow) * IN_DIM + srcChunk * 8;
  const ushort_t* gB = W + (size_t)(colBase + srcRow) * IN_DIM + srcChunk * 8;

  // fragment-read addressing
  const int rA  = lane & 15;
  const int kh  = lane >> 4;
  const int sw  = rA & 7;
  const int ko0 = ((kh)     ^ sw) * 8;   // kk=0 chunk, swizzled, in shorts
  const int ko1 = ((4 + kh) ^ sw) * 8;   // kk=1
  const short* aRd0 = lA0 + (wr * 128 + rA) * 64;
  const short* bRd0 = lB0 + (wc * 64  + rA) * 64;
  const short* aRd1 = lA1 + (wr * 128 + rA) * 64;
  const short* bRd1 = lB1 + (wc * 64  + rA) * 64;

  floatx4 acc[8][4];
  #pragma unroll
  for (int i = 0; i < 8; ++i)
    #pragma unroll
    for (int j = 0; j < 4; ++j) acc[i][j] = (floatx4){0.f, 0.f, 0.f, 0.f};
  short8 bf[8];

  // prologue: tile0 complete (8 loads), then tile1 Bh0,Bh1,Ah0 (6 loads)
  stage_half(gA, lA0, 0, 0, wid);
  stage_half(gA, lA0, 0, 1, wid);
  stage_half(gB, lB0, 0, 0, wid);
  stage_half(gB, lB0, 0, 1, wid);
  stage_half(gB, lB1, 1, 0, wid);
  stage_half(gB, lB1, 1, 1, wid);
  stage_half(gA, lA1, 1, 0, wid);
  asm volatile("s_waitcnt vmcnt(6)");   // tile0's 8 loads landed
  __builtin_amdgcn_s_barrier();

  #pragma unroll 1
  for (int i = 0; i < 16; ++i) {                     // 2 K-tiles / iter, 32 tiles
    const int  t2   = 2 * i + 2, t3 = 2 * i + 3;
    const bool more = (i < 15);
    // tile 2i from buf0
    phase<0, true >(aRd0, bRd0, ko0, ko1, acc, bf,
                    [&] { stage_half(gA, lA1, 2 * i + 1, 1, wid); }, -1);
    phase<1, false>(aRd0, bRd0, ko0, ko1, acc, bf,
                    [&] { if (more) stage_half(gB, lB0, t2, 0, wid); }, -1);
    phase<2, false>(aRd0, bRd0, ko0, ko1, acc, bf,
                    [&] { if (more) stage_half(gB, lB0, t2, 1, wid); }, -1);
    phase<3, false>(aRd0, bRd0, ko0, ko1, acc, bf,
                    [&] { if (more) stage_half(gA, lA0, t2, 0, wid); }, more ? 6 : 0);
    // tile 2i+1 from buf1
    phase<0, true >(aRd1, bRd1, ko0, ko1, acc, bf,
                    [&] { if (more) stage_half(gA, lA0, t2, 1, wid); }, -1);
    phase<1, false>(aRd1, bRd1, ko0, ko1, acc, bf,
                    [&] { if (more) stage_half(gB, lB1, t3, 0, wid); }, -1);
    phase<2, false>(aRd1, bRd1, ko0, ko1, acc, bf,
                    [&] { if (more) stage_half(gB, lB1, t3, 1, wid); }, -1);
    phase<3, false>(aRd1, bRd1, ko0, ko1, acc, bf,
                    [&] { if (more) stage_half(gA, lA1, t3, 0, wid); }, more ? 6 : -1);
  }

  // epilogue: D col = lane&15, row = (lane>>4)*4 + reg (regs only, no barrier needed)
  const int mB = rowBase + wr * 128 + (lane >> 4) * 4;
  const int nB = colBase + wc * 64 + (lane & 15);
  #pragma unroll
  for (int ni = 0; ni < 4; ++ni) {
    float bv = bias[nB + ni * 16];
    #pragma unroll
    for (int mi = 0; mi < 8; ++mi)
      #pragma unroll
      for (int r = 0; r < 4; ++r)
        C[(size_t)(mB + mi * 16 + r) * OUT_DIM + (nB + ni * 16)] = acc[mi][ni][r] + bv;
  }
}

extern "C" void kernel_launch(void* const* d_in, const int* in_sizes, int n_in,
                              void* d_out, int out_size, void* d_ws, size_t ws_size,
                              hipStream_t stream) {
  const float* x    = (const float*)d_in[0];
  const int*   idx  = (const int*)d_in[1];
  const float* lut  = (const float*)d_in[2];
  const float* sA   = (const float*)d_in[3];
  const float* sB   = (const float*)d_in[4];
  const float* mag  = (const float*)d_in[5];
  const float* bias = (const float*)d_in[6];
  float* y = (float*)d_out;

  char* ws = (char*)d_ws;
  ushort_t* W  = (ushort_t*)(ws + 256);                                 // 8 MiB
  ushort_t* xb = (ushort_t*)(ws + 256 + (size_t)OUT_DIM * IN_DIM * 2);  // 32 MiB

  prep_kernel<<<8192 + OUT_DIM, 256, 0, stream>>>(x, xb, idx, lut, sA, sB, mag, W);
  dim3 g(OUT_DIM / 256, MROWS / 256);
  gemm_kernel<<<g, 512, 0, stream>>>(xb, W, bias, y);
}